// Round 1
// baseline (1028.782 us; speedup 1.0000x reference)
//
#include <hip/hip_runtime.h>
#include <hip/hip_bf16.h>

#define NHEAD 8
#define BB 4
#define LL 2048

typedef short bf16x8 __attribute__((ext_vector_type(8)));
typedef float f32x4 __attribute__((ext_vector_type(4)));

__device__ __forceinline__ short f2bs(float f) {
    __hip_bfloat16 h = __float2bfloat16(f);
    return __builtin_bit_cast(short, h);
}

__device__ __forceinline__ f32x4 mfma16(bf16x8 a, bf16x8 b, f32x4 c) {
    return __builtin_amdgcn_mfma_f32_16x16x32_bf16(a, b, c, 0, 0, 0);
}

// ---------------- fp32 -> bf16 bulk convert (4 elems/thread) ----------------
__global__ void cvt_kernel(const float* __restrict__ src, short* __restrict__ dst) {
    int i = blockIdx.x * blockDim.x + threadIdx.x;
    float4 v = reinterpret_cast<const float4*>(src)[i];
    short4 o = make_short4(f2bs(v.x), f2bs(v.y), f2bs(v.z), f2bs(v.w));
    reinterpret_cast<short4*>(dst)[i] = o;
}

// ---------------- weight transpose + convert: wT[n][k] = w[k][n] ----------------
__global__ void wtrans_kernel(const float* __restrict__ w, short* __restrict__ wT) {
    int k = blockIdx.x * 16 + threadIdx.x;
    int n = blockIdx.y * 16 + threadIdx.y;
    wT[n * 512 + k] = f2bs(w[k * 512 + n]);
}

// ---------------- projection GEMM: out = A(M x 512) @ BT^T, headed layouts ----------------
// mode 0: Q -> [b,h,l,d] scaled; mode 1: K -> [b,h,l,d]; mode 2: V -> [b,h,d,l] (transposed)
__global__ __launch_bounds__(256) void gemm_proj_kernel(
        const short* __restrict__ A, const short* __restrict__ BT,
        short* __restrict__ outp, int mode, float scale) {
    int wv = threadIdx.x >> 6;
    int lane = threadIdx.x & 63;
    int quad = lane >> 4, l15 = lane & 15;
    int m0 = blockIdx.x * 128 + wv * 32;
    int n0 = blockIdx.y * 128;

    f32x4 zero = {0.f, 0.f, 0.f, 0.f};
    f32x4 acc[2][8];
#pragma unroll
    for (int mi = 0; mi < 2; mi++)
#pragma unroll
        for (int ni = 0; ni < 8; ni++) acc[mi][ni] = zero;

    const short* arow = A + (size_t)(m0 + l15) * 512;
    const short* brow = BT + (size_t)(n0 + l15) * 512;

    for (int kc = 0; kc < 512; kc += 32) {
        bf16x8 a0 = *reinterpret_cast<const bf16x8*>(arow + kc + quad * 8);
        bf16x8 a1 = *reinterpret_cast<const bf16x8*>(arow + 16 * 512 + kc + quad * 8);
#pragma unroll
        for (int ni = 0; ni < 8; ni++) {
            bf16x8 b = *reinterpret_cast<const bf16x8*>(brow + ni * 16 * 512 + kc + quad * 8);
            acc[0][ni] = mfma16(a0, b, acc[0][ni]);
            acc[1][ni] = mfma16(a1, b, acc[1][ni]);
        }
    }

#pragma unroll
    for (int mi = 0; mi < 2; mi++)
#pragma unroll
        for (int ni = 0; ni < 8; ni++)
#pragma unroll
            for (int r = 0; r < 4; r++) {
                int row = m0 + mi * 16 + quad * 4 + r;   // token index
                int col = n0 + ni * 16 + l15;            // h*64+d
                float val = acc[mi][ni][r] * scale;
                int b = row >> 11, l = row & 2047;
                int h = col >> 6, d = col & 63;
                size_t idx;
                if (mode == 2)
                    idx = ((size_t)((b * NHEAD + h) * 64 + d)) * 2048 + l;
                else
                    idx = ((size_t)((b * NHEAD + h) * 2048 + l)) * 64 + d;
                outp[idx] = f2bs(val);
            }
}

// ---------------- fc GEMM + bias + residual -> x (fp32) ----------------
__global__ __launch_bounds__(256) void gemm_fc_kernel(
        const short* __restrict__ A, const short* __restrict__ BT,
        const float* __restrict__ bias, const float* __restrict__ resid,
        float* __restrict__ xout) {
    int wv = threadIdx.x >> 6;
    int lane = threadIdx.x & 63;
    int quad = lane >> 4, l15 = lane & 15;
    int m0 = blockIdx.x * 128 + wv * 32;
    int n0 = blockIdx.y * 128;

    f32x4 zero = {0.f, 0.f, 0.f, 0.f};
    f32x4 acc[2][8];
#pragma unroll
    for (int mi = 0; mi < 2; mi++)
#pragma unroll
        for (int ni = 0; ni < 8; ni++) acc[mi][ni] = zero;

    const short* arow = A + (size_t)(m0 + l15) * 512;
    const short* brow = BT + (size_t)(n0 + l15) * 512;

    for (int kc = 0; kc < 512; kc += 32) {
        bf16x8 a0 = *reinterpret_cast<const bf16x8*>(arow + kc + quad * 8);
        bf16x8 a1 = *reinterpret_cast<const bf16x8*>(arow + 16 * 512 + kc + quad * 8);
#pragma unroll
        for (int ni = 0; ni < 8; ni++) {
            bf16x8 b = *reinterpret_cast<const bf16x8*>(brow + ni * 16 * 512 + kc + quad * 8);
            acc[0][ni] = mfma16(a0, b, acc[0][ni]);
            acc[1][ni] = mfma16(a1, b, acc[1][ni]);
        }
    }

#pragma unroll
    for (int mi = 0; mi < 2; mi++)
#pragma unroll
        for (int ni = 0; ni < 8; ni++)
#pragma unroll
            for (int r = 0; r < 4; r++) {
                int row = m0 + mi * 16 + quad * 4 + r;
                int col = n0 + ni * 16 + l15;
                size_t idx = (size_t)row * 512 + col;
                xout[idx] = acc[mi][ni][r] + bias[col] + resid[idx];
            }
}

// ---------------- attention: scores+mask+softmax+attn-write+PV ----------------
// grid (128, 8, 4) = (qtile, h, b); block 256 = 4 waves; wave w owns cols [w*512, w*512+512)
__global__ __launch_bounds__(256, 2) void attn_kernel(
        const short* __restrict__ Qp, const short* __restrict__ Kp,
        const short* __restrict__ Vt, const int* __restrict__ mask,
        float* __restrict__ attn_out, short* __restrict__ Ob) {
    __shared__ __align__(16) float rowstat[2][64];     // [phase][row*4 + wave]
    __shared__ __align__(16) short pbuf[4][2][512];    // [wave][parity][16 rows x 32 cols]
    __shared__ __align__(16) float obuf[4][1024];      // [wave][16 rows x 64 d]

    int wv = threadIdx.x >> 6;
    int lane = threadIdx.x & 63;
    int quad = lane >> 4, l15 = lane & 15;
    int qt = blockIdx.x, h = blockIdx.y, b = blockIdx.z;
    int bh = b * NHEAD + h;
    int q0 = qt * 16;
    int c0 = wv * 512;

    // Q fragments (A-layout: row=lane&15, k=quad*8+t), scale 1/8 folded into Qp
    const short* qptr = Qp + ((size_t)(bh * 2048 + q0 + l15)) * 64 + quad * 8;
    bf16x8 aq0 = *reinterpret_cast<const bf16x8*>(qptr);
    bf16x8 aq1 = *reinterpret_cast<const bf16x8*>(qptr + 32);

    // ---- S = Q K^T over this wave's 512 cols: 32 tiles of 16x16, kept in regs ----
    const short* kbase = Kp + ((size_t)(bh * 2048 + c0 + l15)) * 64 + quad * 8;
    f32x4 s[32];
#pragma unroll
    for (int t = 0; t < 32; t++) {
        bf16x8 bk0 = *reinterpret_cast<const bf16x8*>(kbase + t * 16 * 64);
        bf16x8 bk1 = *reinterpret_cast<const bf16x8*>(kbase + t * 16 * 64 + 32);
        f32x4 a = {0.f, 0.f, 0.f, 0.f};
        a = mfma16(aq0, bk0, a);
        a = mfma16(aq1, bk1, a);
        s[t] = a;
    }

    // ---- mask + row max (C-layout: row=quad*4+r, col=lane&15) ----
    const int* mbase = mask + ((size_t)(b * 2048 + q0 + quad * 4)) * 2048 + c0 + l15;
    float m[4] = {-1e30f, -1e30f, -1e30f, -1e30f};
#pragma unroll
    for (int t = 0; t < 32; t++) {
#pragma unroll
        for (int r = 0; r < 4; r++) {
            int mv = mbase[(size_t)r * 2048 + t * 16];
            float sv = mv ? -1e10f : s[t][r];
            s[t][r] = sv;
            m[r] = fmaxf(m[r], sv);
        }
    }
#pragma unroll
    for (int off = 1; off < 16; off <<= 1) {
#pragma unroll
        for (int r = 0; r < 4; r++) m[r] = fmaxf(m[r], __shfl_xor(m[r], off, 64));
    }
#pragma unroll
    for (int r = 0; r < 4; r++)
        if (l15 == r) rowstat[0][(quad * 4 + r) * 4 + wv] = m[r];
    __syncthreads();
    float rmax[4];
#pragma unroll
    for (int r = 0; r < 4; r++) {
        f32x4 v = *reinterpret_cast<f32x4*>(&rowstat[0][(quad * 4 + r) * 4]);
        rmax[r] = fmaxf(fmaxf(v[0], v[1]), fmaxf(v[2], v[3]));
    }

    // ---- exp + row sum ----
    float sum[4] = {0.f, 0.f, 0.f, 0.f};
#pragma unroll
    for (int t = 0; t < 32; t++) {
#pragma unroll
        for (int r = 0; r < 4; r++) {
            float p = __expf(s[t][r] - rmax[r]);
            s[t][r] = p;
            sum[r] += p;
        }
    }
#pragma unroll
    for (int off = 1; off < 16; off <<= 1) {
#pragma unroll
        for (int r = 0; r < 4; r++) sum[r] += __shfl_xor(sum[r], off, 64);
    }
#pragma unroll
    for (int r = 0; r < 4; r++)
        if (l15 == r) rowstat[1][(quad * 4 + r) * 4 + wv] = sum[r];
    __syncthreads();
    float inv[4];
#pragma unroll
    for (int r = 0; r < 4; r++) {
        f32x4 v = *reinterpret_cast<f32x4*>(&rowstat[1][(quad * 4 + r) * 4]);
        inv[r] = 1.0f / (v[0] + v[1] + v[2] + v[3]);
    }

    // ---- normalized attn write + P@V (P via LDS C-layout -> A-layout transform) ----
    f32x4 o[4];
    f32x4 zero = {0.f, 0.f, 0.f, 0.f};
#pragma unroll
    for (int n = 0; n < 4; n++) o[n] = zero;

    float* aout = attn_out + ((size_t)((h * BB + b) * 2048 + q0 + quad * 4)) * 2048 + c0 + l15;
    const short* vbase = Vt + ((size_t)(bh * 64 + l15)) * 2048 + c0 + quad * 8;
    int par = 0;
#pragma unroll
    for (int t2 = 0; t2 < 16; t2++) {
#pragma unroll
        for (int j = 0; j < 2; j++) {
            int t = t2 * 2 + j;
#pragma unroll
            for (int r = 0; r < 4; r++) {
                float pn = s[t][r] * inv[r];
                aout[(size_t)r * 2048 + t * 16] = pn;
                pbuf[wv][par][(quad * 4 + r) * 32 + j * 16 + l15] = f2bs(pn);
            }
        }
        __asm__ volatile("s_waitcnt lgkmcnt(0)" ::: "memory");
        bf16x8 ap = *reinterpret_cast<const bf16x8*>(&pbuf[wv][par][l15 * 32 + quad * 8]);
#pragma unroll
        for (int n = 0; n < 4; n++) {
            bf16x8 bv = *reinterpret_cast<const bf16x8*>(vbase + n * 16 * 2048 + t2 * 32);
            o[n] = mfma16(ap, bv, o[n]);
        }
        par ^= 1;
    }

    // ---- cross-wave O reduction -> Ob (bf16, [token][h*64+d]) ----
#pragma unroll
    for (int n = 0; n < 4; n++)
#pragma unroll
        for (int r = 0; r < 4; r++)
            obuf[wv][(quad * 4 + r) * 64 + n * 16 + l15] = o[n][r];
    __syncthreads();
    int e = threadIdx.x * 4;
    f32x4 v0 = *reinterpret_cast<f32x4*>(&obuf[0][e]);
    f32x4 v1 = *reinterpret_cast<f32x4*>(&obuf[1][e]);
    f32x4 v2 = *reinterpret_cast<f32x4*>(&obuf[2][e]);
    f32x4 v3 = *reinterpret_cast<f32x4*>(&obuf[3][e]);
    f32x4 vv = v0 + v1 + v2 + v3;
    int row = e >> 6, d = e & 63;
    short4 ov = make_short4(f2bs(vv[0]), f2bs(vv[1]), f2bs(vv[2]), f2bs(vv[3]));
    *reinterpret_cast<short4*>(&Ob[((size_t)(b * 2048 + q0 + row)) * 512 + h * 64 + d]) = ov;
}

// ---------------- row LayerNorm ----------------
__global__ __launch_bounds__(256) void ln_kernel(
        const float* __restrict__ x, const float* __restrict__ gamma,
        const float* __restrict__ beta, float* __restrict__ y) {
    __shared__ float red[8];
    int row = blockIdx.x;
    int tid = threadIdx.x;
    float2 v = reinterpret_cast<const float2*>(x + (size_t)row * 512)[tid];
    float sum = v.x + v.y;
    float sq = v.x * v.x + v.y * v.y;
#pragma unroll
    for (int off = 1; off < 64; off <<= 1) {
        sum += __shfl_xor(sum, off, 64);
        sq += __shfl_xor(sq, off, 64);
    }
    int wv = tid >> 6;
    if ((tid & 63) == 0) { red[wv] = sum; red[4 + wv] = sq; }
    __syncthreads();
    float ts = red[0] + red[1] + red[2] + red[3];
    float tq = red[4] + red[5] + red[6] + red[7];
    float mu = ts * (1.0f / 512.0f);
    float var = tq * (1.0f / 512.0f) - mu * mu;
    float rs = rsqrtf(var + 1e-5f);
    float2 g = reinterpret_cast<const float2*>(gamma)[tid];
    float2 be = reinterpret_cast<const float2*>(beta)[tid];
    float2 o;
    o.x = (v.x - mu) * rs * g.x + be.x;
    o.y = (v.y - mu) * rs * g.y + be.y;
    reinterpret_cast<float2*>(y + (size_t)row * 512)[tid] = o;
}

extern "C" void kernel_launch(void* const* d_in, const int* in_sizes, int n_in,
                              void* d_out, int out_size, void* d_ws, size_t ws_size,
                              hipStream_t stream) {
    (void)in_sizes; (void)n_in; (void)out_size; (void)ws_size;
    const float* q    = (const float*)d_in[0];
    const float* k    = (const float*)d_in[1];
    const float* v    = (const float*)d_in[2];
    const int*   mask = (const int*)d_in[3];   // bool -> int32 per harness convention
    const float* w_q  = (const float*)d_in[4];
    const float* w_k  = (const float*)d_in[5];
    const float* w_v  = (const float*)d_in[6];
    const float* w_fc = (const float*)d_in[7];
    const float* b_fc = (const float*)d_in[8];
    const float* ln_g = (const float*)d_in[9];
    const float* ln_b = (const float*)d_in[10];

    const size_t SZ_TOK = (size_t)8192 * 512;   // 4,194,304 elements
    const size_t SZ_W   = (size_t)512 * 512;

    char* ws = (char*)d_ws;
    short* qb  = (short*)ws; ws += SZ_TOK * 2;
    short* kb  = (short*)ws; ws += SZ_TOK * 2;
    short* vb  = (short*)ws; ws += SZ_TOK * 2;
    short* wqT = (short*)ws; ws += SZ_W * 2;
    short* wkT = (short*)ws; ws += SZ_W * 2;
    short* wvT = (short*)ws; ws += SZ_W * 2;
    short* wfT = (short*)ws; ws += SZ_W * 2;
    short* Qp  = (short*)ws; ws += SZ_TOK * 2;
    short* Kp  = (short*)ws; ws += SZ_TOK * 2;
    short* Vt  = (short*)ws; ws += SZ_TOK * 2;
    short* Ob  = (short*)ws; ws += SZ_TOK * 2;
    float* x   = (float*)ws; ws += SZ_TOK * 4;

    float* y    = (float*)d_out;
    float* attn = (float*)d_out + SZ_TOK;

    cvt_kernel<<<4096, 256, 0, stream>>>(q, qb);
    cvt_kernel<<<4096, 256, 0, stream>>>(k, kb);
    cvt_kernel<<<4096, 256, 0, stream>>>(v, vb);

    dim3 tg(32, 32), tb(16, 16);
    wtrans_kernel<<<tg, tb, 0, stream>>>(w_q, wqT);
    wtrans_kernel<<<tg, tb, 0, stream>>>(w_k, wkT);
    wtrans_kernel<<<tg, tb, 0, stream>>>(w_v, wvT);
    wtrans_kernel<<<tg, tb, 0, stream>>>(w_fc, wfT);

    dim3 gg(64, 4);
    gemm_proj_kernel<<<gg, 256, 0, stream>>>(qb, wqT, Qp, 0, 0.125f);  // fold 1/sqrt(64)
    gemm_proj_kernel<<<gg, 256, 0, stream>>>(kb, wkT, Kp, 1, 1.0f);
    gemm_proj_kernel<<<gg, 256, 0, stream>>>(vb, wvT, Vt, 2, 1.0f);

    dim3 ag(128, 8, 4);
    attn_kernel<<<ag, 256, 0, stream>>>(Qp, Kp, Vt, mask, attn, Ob);

    gemm_fc_kernel<<<gg, 256, 0, stream>>>(Ob, wfT, b_fc, q, x);
    ln_kernel<<<8192, 256, 0, stream>>>(x, ln_g, ln_b, y);
}